// Round 11
// baseline (118.832 us; speedup 1.0000x reference)
//
#include <hip/hip_runtime.h>

typedef __attribute__((ext_vector_type(8))) _Float16 half8;
typedef __attribute__((ext_vector_type(4))) _Float16 half4;
typedef __attribute__((ext_vector_type(4))) float f32x4;
#if __has_builtin(__builtin_amdgcn_cvt_pkrtz)
typedef __attribute__((ext_vector_type(2))) __fp16 fp16x2;
#endif

#define ALPHA 0.2f
#define LOG2E 1.44269504f
#define ALC (ALPHA * LOG2E)

__device__ __forceinline__ void gload_lds16(const void* g, void* l) {
  __builtin_amdgcn_global_load_lds((const __attribute__((address_space(1))) unsigned int*)g,
                                   (__attribute__((address_space(3))) unsigned int*)l, 16, 0, 0);
}

__device__ __forceinline__ float fexp2(float x) {
#if __has_builtin(__builtin_amdgcn_exp2f)
  return __builtin_amdgcn_exp2f(x);
#else
  return exp2f(x);
#endif
}

#if __has_builtin(__builtin_amdgcn_cvt_pkrtz)
#define PACK2(DST, I, A, B)                        \
  { fp16x2 q_ = __builtin_amdgcn_cvt_pkrtz(A, B);  \
    DST[I] = (_Float16)q_[0]; DST[I + 1] = (_Float16)q_[1]; }
#else
#define PACK2(DST, I, A, B) { DST[I] = (_Float16)(A); DST[I + 1] = (_Float16)(B); }
#endif

#define EXP8(OUT, V0, V1, C1_, C2_)                                   \
  {                                                                   \
    float p0 = fexp2(fmaxf(C1_ + V0.x, fmaf(ALPHA, V0.x, C2_)));      \
    float p1 = fexp2(fmaxf(C1_ + V0.y, fmaf(ALPHA, V0.y, C2_)));      \
    float p2 = fexp2(fmaxf(C1_ + V0.z, fmaf(ALPHA, V0.z, C2_)));      \
    float p3 = fexp2(fmaxf(C1_ + V0.w, fmaf(ALPHA, V0.w, C2_)));      \
    float p4 = fexp2(fmaxf(C1_ + V1.x, fmaf(ALPHA, V1.x, C2_)));      \
    float p5 = fexp2(fmaxf(C1_ + V1.y, fmaf(ALPHA, V1.y, C2_)));      \
    float p6 = fexp2(fmaxf(C1_ + V1.z, fmaf(ALPHA, V1.z, C2_)));      \
    float p7 = fexp2(fmaxf(C1_ + V1.w, fmaf(ALPHA, V1.w, C2_)));      \
    PACK2(OUT, 0, p0, p1); PACK2(OUT, 2, p2, p3);                     \
    PACK2(OUT, 4, p4, p5); PACK2(OUT, 6, p6, p7);                     \
  }

// ---------------- K0: merged prologue — convW swizzled + uvec ----------------
__global__ __launch_bounds__(256) void k_prologue(const float* __restrict__ W,
                                                  const float* __restrict__ a1,
                                                  const float* __restrict__ a2,
                                                  _Float16* __restrict__ W16,
                                                  float* __restrict__ u1,
                                                  float* __restrict__ u2) {
  const int bid = blockIdx.x, t = threadIdx.x;
  if (bid < 128) {
    int idx4 = bid * 256 + t;
    int n = idx4 >> 7;
    int q = idx4 & 127;
    float4 v = *reinterpret_cast<const float4*>(W + n * 512 + q * 4);
    half4 hv = {(_Float16)v.x, (_Float16)v.y, (_Float16)v.z, (_Float16)v.w};
    int kp = (q * 4) ^ ((n & 7) << 3);
    *reinterpret_cast<half4*>(W16 + n * 512 + kp) = hv;
  } else {
    __shared__ float p1[4][64], p2[4][64];
    int l = t & 63, g = t >> 6;
    int k = (bid - 128) * 64 + l;
    float x1 = 0.f, x2 = 0.f;
    for (int o = g * 64; o < g * 64 + 64; ++o) {
      float wv = W[o * 512 + k];
      x1 += wv * a1[o];
      x2 += wv * a2[o];
    }
    p1[g][l] = x1; p2[g][l] = x2;
    __syncthreads();
    if (g == 0) {
      u1[k] = p1[0][l] + p1[1][l] + p1[2][l] + p1[3][l];
      u2[k] = p2[0][l] + p2[1][l] + p2[2][l] + p2[3][l];
    }
  }
}

// ---------------- K2: Wh GEMM + fused s1/s2 (R2-proven core; epilogue mode switch) ----------------
// mode 1: write Wh16 row-major [b][n][c] fp16. mode 0: legacy pre-swizzled WhT [b][c][n].
__global__ __launch_bounds__(256) void k_gemm_wh(const float* __restrict__ h,
                                                 const _Float16* __restrict__ W16,
                                                 const float* __restrict__ u1,
                                                 const float* __restrict__ u2,
                                                 float* __restrict__ s1o,
                                                 float* __restrict__ s2o,
                                                 _Float16* __restrict__ WhOut,
                                                 const int mode) {
  __shared__ _Float16 Ab[2][32 * 64];
  __shared__ _Float16 Bb[2][256 * 64];
  const int t = threadIdx.x, lane = t & 63, w = t >> 6;
  const int i0 = blockIdx.x * 32;
  const int b = i0 >> 11, n0 = i0 & 2047;
  const int ar = t >> 3, au = t & 7;
  const float* hrow = h + (size_t)(i0 + ar) * 512 + au * 8;

  f32x4 acc[2][4];
#pragma unroll
  for (int mi = 0; mi < 2; ++mi)
#pragma unroll
    for (int ni = 0; ni < 4; ++ni) acc[mi][ni] = (f32x4){0.f, 0.f, 0.f, 0.f};

  float4 aR0 = *reinterpret_cast<const float4*>(hrow);
  float4 aR1 = *reinterpret_cast<const float4*>(hrow + 4);
#pragma unroll
  for (int q = 0; q < 8; ++q) {
    int idx = (q * 4 + w) * 64 + lane;
    int nn = idx >> 3, uu = idx & 7;
    gload_lds16(W16 + nn * 512 + uu * 8, (char*)&Bb[0][0] + idx * 16);
  }
  float x1 = 0.f, x2 = 0.f;

  for (int kt = 0; kt < 8; ++kt) {
    const int cur = kt & 1;
    {
      half8 av;
      av[0] = (_Float16)aR0.x; av[1] = (_Float16)aR0.y;
      av[2] = (_Float16)aR0.z; av[3] = (_Float16)aR0.w;
      av[4] = (_Float16)aR1.x; av[5] = (_Float16)aR1.y;
      av[6] = (_Float16)aR1.z; av[7] = (_Float16)aR1.w;
      *reinterpret_cast<half8*>((char*)&Ab[cur][0] + ar * 128 + ((au * 16) ^ ((ar & 7) << 4))) = av;
      const float* up1 = u1 + kt * 64 + au * 8;
      const float* up2 = u2 + kt * 64 + au * 8;
      float4 u1a = *reinterpret_cast<const float4*>(up1);
      float4 u1b = *reinterpret_cast<const float4*>(up1 + 4);
      float4 u2a = *reinterpret_cast<const float4*>(up2);
      float4 u2b = *reinterpret_cast<const float4*>(up2 + 4);
      x1 += aR0.x * u1a.x + aR0.y * u1a.y + aR0.z * u1a.z + aR0.w * u1a.w
          + aR1.x * u1b.x + aR1.y * u1b.y + aR1.z * u1b.z + aR1.w * u1b.w;
      x2 += aR0.x * u2a.x + aR0.y * u2a.y + aR0.z * u2a.z + aR0.w * u2a.w
          + aR1.x * u2b.x + aR1.y * u2b.y + aR1.z * u2b.z + aR1.w * u2b.w;
    }
    __syncthreads();
    if (kt < 7) {
      const int k0 = (kt + 1) * 64;
      aR0 = *reinterpret_cast<const float4*>(hrow + k0);
      aR1 = *reinterpret_cast<const float4*>(hrow + k0 + 4);
#pragma unroll
      for (int q = 0; q < 8; ++q) {
        int idx = (q * 4 + w) * 64 + lane;
        int nn = idx >> 3, uu = idx & 7;
        gload_lds16(W16 + nn * 512 + k0 + uu * 8, (char*)&Bb[cur ^ 1][0] + idx * 16);
      }
    }
    const char* Ac = (const char*)&Ab[cur][0];
    const char* Bc = (const char*)&Bb[cur][0];
#pragma unroll
    for (int kk = 0; kk < 2; ++kk) {
      const int jb = (lane >> 4) * 16 + kk * 64;
      half8 afr[2];
#pragma unroll
      for (int mi = 0; mi < 2; ++mi) {
        int rr = (lane & 15) + 16 * mi;
        afr[mi] = *reinterpret_cast<const half8*>(Ac + rr * 128 + (jb ^ ((rr & 7) << 4)));
      }
#pragma unroll
      for (int ni = 0; ni < 4; ++ni) {
        int nn = 64 * w + 16 * ni + (lane & 15);
        half8 bfr = *reinterpret_cast<const half8*>(Bc + nn * 128 + (jb ^ ((nn & 7) << 4)));
#pragma unroll
        for (int mi = 0; mi < 2; ++mi)
          acc[mi][ni] = __builtin_amdgcn_mfma_f32_16x16x32_f16(afr[mi], bfr, acc[mi][ni], 0, 0, 0);
      }
    }
  }
  x1 += __shfl_xor(x1, 1); x1 += __shfl_xor(x1, 2); x1 += __shfl_xor(x1, 4);
  x2 += __shfl_xor(x2, 1); x2 += __shfl_xor(x2, 2); x2 += __shfl_xor(x2, 4);
  if (au == 0) { s1o[i0 + ar] = x1; s2o[i0 + ar] = x2; }
  if (mode) {
    // row-major Wh16[g][c]: per (mi,reg) 2B stores; 16-lane arow groups are 32B-contiguous
#pragma unroll
    for (int mi = 0; mi < 2; ++mi)
#pragma unroll
      for (int ni = 0; ni < 4; ++ni) {
        int c = 64 * w + 16 * ni + (lane & 15);
        int g = i0 + 16 * mi + (lane >> 4) * 4;
        f32x4 a = acc[mi][ni];
#pragma unroll
        for (int reg = 0; reg < 4; ++reg)
          WhOut[(size_t)(g + reg) * 256 + c] = (_Float16)a[reg];
      }
  } else {
    _Float16* whtb = WhOut + (size_t)b * 256 * 2048;
#pragma unroll
    for (int mi = 0; mi < 2; ++mi)
#pragma unroll
      for (int ni = 0; ni < 4; ++ni) {
        int c = 64 * w + 16 * ni + (lane & 15);
        int nb = n0 + 16 * mi + (lane >> 4) * 4;
        int np = nb ^ ((c & 7) << 3);
        f32x4 a = acc[mi][ni];
        half4 hv = {(_Float16)a[0], (_Float16)a[1], (_Float16)a[2], (_Float16)a[3]};
        *reinterpret_cast<half4*>(whtb + (size_t)c * 2048 + np) = hv;
      }
  }
}

// ---------------- K3: per-batch bitonic sort of s2 (ascending) with permutation ----------------
__global__ __launch_bounds__(512) void k_sort(const float* __restrict__ s2,
                                              float* __restrict__ tS,
                                              int* __restrict__ perm) {
  __shared__ float key[2048];
  __shared__ int idx[2048];
  const int b = blockIdx.x, t = threadIdx.x;
  for (int i = t; i < 2048; i += 512) { key[i] = s2[b * 2048 + i]; idx[i] = i; }
  __syncthreads();
  for (int k = 2; k <= 2048; k <<= 1) {
    for (int j = k >> 1; j > 0; j >>= 1) {
      for (int i = t; i < 2048; i += 512) {
        int ixj = i ^ j;
        if (ixj > i) {
          bool asc = ((i & k) == 0);
          float ka = key[i], kb = key[ixj];
          bool sw = asc ? (ka > kb) : (ka < kb);
          if (sw) {
            key[i] = kb; key[ixj] = ka;
            int tmp = idx[i]; idx[i] = idx[ixj]; idx[ixj] = tmp;
          }
        }
      }
      __syncthreads();
    }
  }
  for (int i = t; i < 2048; i += 512) { tS[b * 2048 + i] = key[i]; perm[b * 2048 + i] = idx[i]; }
}

// ---------------- K4: chunk sums (32 sorted rows per chunk) ----------------
__global__ __launch_bounds__(256) void k_csum(const _Float16* __restrict__ Wh16,
                                              const float* __restrict__ tS,
                                              const int* __restrict__ perm,
                                              float* __restrict__ Cp,
                                              float* __restrict__ Cn) {
  const int bid = blockIdx.x;  // b*64 + ch
  const int b = bid >> 6, ch = bid & 63, t = threadIdx.x;
  const int base = b * 2048 + ch * 32;
  float rp = 0.f, rn = 0.f;
  for (int r = 0; r < 32; ++r) {
    int row = perm[base + r];
    float tv = tS[base + r];
    float wp = fexp2(LOG2E * tv);
    float wn = fexp2(ALC * tv);
    float v = (float)Wh16[((size_t)b * 2048 + row) * 256 + t];
    rp = fmaf(wp, v, rp);
    rn = fmaf(wn, v, rn);
  }
  Cp[(size_t)bid * 256 + t] = rp;
  Cn[(size_t)bid * 256 + t] = rn;
}

// ---------------- K5a: exclusive scan over the 64 chunks (per batch, per col) ----------------
__global__ __launch_bounds__(256) void k_cscan(float* __restrict__ Cp, float* __restrict__ Cn) {
  const int b = blockIdx.x, c = threadIdx.x;
  float ap = 0.f, an = 0.f;
  for (int ch = 0; ch < 64; ++ch) {
    size_t o = ((size_t)(b * 64 + ch)) * 256 + c;
    float vp = Cp[o], vn = Cn[o];
    Cp[o] = ap; Cn[o] = an;
    ap += vp; an += vn;
  }
}

// ---------------- K5b: scalar weight prefix sums pp/pn[0..2048] per batch ----------------
__global__ __launch_bounds__(256) void k_sscan(const float* __restrict__ tS,
                                               float* __restrict__ pp,
                                               float* __restrict__ pn) {
  __shared__ float sp[256], sn[256];
  const int b = blockIdx.x, t = threadIdx.x;
  float lp[8], ln[8];
  float ap = 0.f, an = 0.f;
#pragma unroll
  for (int x = 0; x < 8; ++x) {
    float tv = tS[b * 2048 + t * 8 + x];
    lp[x] = ap; ln[x] = an;
    ap += fexp2(LOG2E * tv);
    an += fexp2(ALC * tv);
  }
  sp[t] = ap; sn[t] = an;
  __syncthreads();
  if (t == 0) {
    float s = 0.f, s2_ = 0.f;
    for (int i = 0; i < 256; ++i) {
      float v = sp[i]; sp[i] = s; s += v;
      float v2 = sn[i]; sn[i] = s2_; s2_ += v2;
    }
  }
  __syncthreads();
  float bp = sp[t], bn = sn[t];
#pragma unroll
  for (int x = 0; x < 8; ++x) {
    pp[b * 2049 + t * 8 + x] = bp + lp[x];
    pn[b * 2049 + t * 8 + x] = bn + ln[x];
  }
  if (t == 255) {
    pp[b * 2049 + 2048] = bp + ap;
    pn[b * 2049 + 2048] = bn + an;
  }
}

// ---------------- K6: write exclusive prefix arrays Pp/Pn[k][c] ----------------
__global__ __launch_bounds__(256) void k_fg(const _Float16* __restrict__ Wh16,
                                            const float* __restrict__ tS,
                                            const int* __restrict__ perm,
                                            const float* __restrict__ Cp,
                                            const float* __restrict__ Cn,
                                            float* __restrict__ Pp,
                                            float* __restrict__ Pn) {
  const int bid = blockIdx.x;
  const int b = bid >> 6, ch = bid & 63, t = threadIdx.x;
  const int base = b * 2048 + ch * 32;
  float rp = Cp[(size_t)bid * 256 + t];
  float rn = Cn[(size_t)bid * 256 + t];
  for (int r = 0; r < 32; ++r) {
    int k = ch * 32 + r;
    size_t po = ((size_t)b * 2049 + k) * 256 + t;
    Pp[po] = rp; Pn[po] = rn;
    int row = perm[base + r];
    float tv = tS[base + r];
    float wp = fexp2(LOG2E * tv);
    float wn = fexp2(ALC * tv);
    float v = (float)Wh16[((size_t)b * 2048 + row) * 256 + t];
    rp = fmaf(wp, v, rp);
    rn = fmaf(wn, v, rn);
  }
  if (ch == 63) {
    size_t po = ((size_t)b * 2049 + 2048) * 256 + t;
    Pp[po] = rp; Pn[po] = rn;
  }
}

// ---------------- K7: output — binary search + combine + ELU ----------------
__global__ __launch_bounds__(256) void k_out(const float* __restrict__ s1,
                                             const float* __restrict__ tS,
                                             const float* __restrict__ pp,
                                             const float* __restrict__ pn,
                                             const float* __restrict__ Pp,
                                             const float* __restrict__ Pn,
                                             float* __restrict__ out) {
  __shared__ float tSh[2048];
  __shared__ float pps[2049], pns[2049];
  const int bid = blockIdx.x;
  const int b = bid & 7, grp = bid >> 3;  // XCD affinity per batch
  const int t = threadIdx.x;
  for (int i = t; i < 2048; i += 256) tSh[i] = tS[b * 2048 + i];
  for (int i = t; i < 2049; i += 256) { pps[i] = pp[b * 2049 + i]; pns[i] = pn[b * 2049 + i]; }
  __syncthreads();
  const int rl = t >> 3, q = t & 7;
  const int i = grp * 32 + rl;
  const float s1v = s1[b * 2048 + i];
  const float tmax = tSh[2047];
  const float e0 = s1v + tmax;
  const float m = fmaxf(e0, ALPHA * e0);  // closed-form row max (LR monotonic)
  const float A = fexp2(LOG2E * (s1v - m));
  const float B = fexp2(LOG2E * fmaf(ALPHA, s1v, -m));
  const float thr = -s1v;
  int k = 0;  // count of sorted t <= thr  (ties: both branches identical math)
#pragma unroll
  for (int s = 2048; s >= 1; s >>= 1) {
    int nk = k + s;
    if (nk <= 2048 && tSh[nk - 1] <= thr) k = nk;
  }
  const float d = B * pns[k] + A * (pps[2048] - pps[k]);
  const float inv = 1.0f / d;
  const float4* fp4 = (const float4*)(Pp + ((size_t)b * 2049 + k) * 256);
  const float4* fn4 = (const float4*)(Pn + ((size_t)b * 2049 + k) * 256);
  const float4* tt4 = (const float4*)(Pp + ((size_t)b * 2049 + 2048) * 256);
  float4* op = (float4*)(out + ((size_t)b * 2048 + i) * 256);
#pragma unroll
  for (int x = 0; x < 8; ++x) {
    int c4 = x * 8 + q;
    float4 fp = fp4[c4], fn = fn4[c4], tt = tt4[c4];
    float4 v;
    v.x = (B * fn.x + A * (tt.x - fp.x)) * inv;
    v.y = (B * fn.y + A * (tt.y - fp.y)) * inv;
    v.z = (B * fn.z + A * (tt.z - fp.z)) * inv;
    v.w = (B * fn.w + A * (tt.w - fp.w)) * inv;
    v.x = v.x > 0.f ? v.x : (__expf(v.x) - 1.f);
    v.y = v.y > 0.f ? v.y : (__expf(v.y) - 1.f);
    v.z = v.z > 0.f ? v.z : (__expf(v.z) - 1.f);
    v.w = v.w > 0.f ? v.w : (__expf(v.w) - 1.f);
    op[c4] = v;
  }
}

// ---------------- FALLBACK attn (R10-proven, used when ws too small) ----------------
__global__ __launch_bounds__(512) void k_attn_fb(const _Float16* __restrict__ WhT,
                                                 const float* __restrict__ s1,
                                                 const float* __restrict__ s2,
                                                 float* __restrict__ out) {
  __shared__ _Float16 Bb[3][128 * 64];
  __shared__ _Float16 Pb[2][64 * 64];
  __shared__ float s2s[2048];
  __shared__ float red[8];
  __shared__ float d_lds[64];
  const int t = threadIdx.x, lane = t & 63, w = t >> 6;
  const int rg = w >> 1, cg = w & 1;
  const int b = blockIdx.x & 7;
  const int i0 = ((blockIdx.x >> 3) & 31) * 64;
  const int ch = blockIdx.x >> 8;
  const _Float16* whtb = WhT + ((size_t)b * 256 + ch * 128) * 2048;
  const int arow = lane & 15;
  const int pr = t >> 3, pj8 = t & 7;
  const float s1v = s1[b * 2048 + i0 + pr];

  float4 sv4 = *reinterpret_cast<const float4*>(s2 + b * 2048 + t * 4);
  float m0 = fmaxf(fmaxf(sv4.x, sv4.y), fmaxf(sv4.z, sv4.w));
  *reinterpret_cast<float4*>(&s2s[t * 4]) =
      make_float4(sv4.x * LOG2E, sv4.y * LOG2E, sv4.z * LOG2E, sv4.w * LOG2E);
#pragma unroll
  for (int off = 32; off >= 1; off >>= 1) m0 = fmaxf(m0, __shfl_xor(m0, off));
  if (lane == 0) red[w] = m0;
  __syncthreads();
  float smaxL;
  {
    float mm = fmaxf(fmaxf(red[0], red[1]), fmaxf(red[2], red[3]));
    mm = fmaxf(mm, fmaxf(fmaxf(red[4], red[5]), fmaxf(red[6], red[7])));
    smaxL = mm * LOG2E;
  }
  const float s1L = LOG2E * s1v;
  const float e0L = s1L + smaxL;
  const float mrowL = fmaxf(e0L, ALPHA * e0L);
  const float C1 = s1L - mrowL;
  const float C2 = fmaf(ALPHA, s1L, -mrowL);
  const int pwoff = pr * 128 + ((pj8 * 16) ^ ((pr & 7) << 4));
  half8 onesb;
  {
    _Float16 ov = (arow == 0) ? (_Float16)1.0f : (_Float16)0.0f;
#pragma unroll
    for (int x = 0; x < 8; ++x) onesb[x] = ov;
  }
  f32x4 acc[4];
#pragma unroll
  for (int ni = 0; ni < 4; ++ni) acc[ni] = (f32x4){0.f, 0.f, 0.f, 0.f};
  f32x4 accd = (f32x4){0.f, 0.f, 0.f, 0.f};
  {
    const float* sp = &s2s[pj8 * 8];
    float4 v0 = *reinterpret_cast<const float4*>(sp);
    float4 v1 = *reinterpret_cast<const float4*>(sp + 4);
    half8 ph;
    EXP8(ph, v0, v1, C1, C2);
    *reinterpret_cast<half8*>((char*)&Pb[0][0] + pwoff) = ph;
  }
#pragma unroll
  for (int x = 0; x < 2; ++x)
#pragma unroll
    for (int q = 0; q < 2; ++q) {
      int idx = q * 512 + t;
      int cl = idx >> 3, uu = idx & 7;
      gload_lds16(whtb + (size_t)cl * 2048 + x * 64 + uu * 8, (char*)&Bb[x][0] + idx * 16);
    }
  for (int jt = 0; jt < 32; ++jt) {
    if (jt < 31) asm volatile("s_waitcnt vmcnt(2) lgkmcnt(0)" ::: "memory");
    else         asm volatile("s_waitcnt vmcnt(0) lgkmcnt(0)" ::: "memory");
    __builtin_amdgcn_s_barrier();
    if (jt < 30) {
      const int j0n = (jt + 2) * 64;
      const int p = (jt + 2) % 3;
#pragma unroll
      for (int q = 0; q < 2; ++q) {
        int idx = q * 512 + t;
        int cl = idx >> 3, uu = idx & 7;
        gload_lds16(whtb + (size_t)cl * 2048 + j0n + uu * 8, (char*)&Bb[p][0] + idx * 16);
      }
    }
    if (jt < 31) {
      const float* sp = &s2s[(jt + 1) * 64 + pj8 * 8];
      float4 v0 = *reinterpret_cast<const float4*>(sp);
      float4 v1 = *reinterpret_cast<const float4*>(sp + 4);
      half8 ph;
      EXP8(ph, v0, v1, C1, C2);
      *reinterpret_cast<half8*>((char*)&Pb[(jt + 1) & 1][0] + pwoff) = ph;
    }
    const char* Bc = (const char*)&Bb[jt % 3][0];
    const char* Pc = (const char*)&Pb[jt & 1][0];
#pragma unroll
    for (int kk = 0; kk < 2; ++kk) {
      const int jb = ((lane >> 4) * 8 + kk * 32) * 2;
      const int ar64 = rg * 16 + arow;
      half8 afr = *reinterpret_cast<const half8*>(Pc + ar64 * 128 + (jb ^ ((ar64 & 7) << 4)));
      if (cg == 0)
        accd = __builtin_amdgcn_mfma_f32_16x16x32_f16(afr, onesb, accd, 0, 0, 0);
#pragma unroll
      for (int ni = 0; ni < 4; ++ni) {
        int cl = cg * 64 + 16 * ni + arow;
        half8 bfr = *reinterpret_cast<const half8*>(Bc + cl * 128 + (jb ^ ((cl & 7) << 4)));
        acc[ni] = __builtin_amdgcn_mfma_f32_16x16x32_f16(afr, bfr, acc[ni], 0, 0, 0);
      }
    }
  }
  if (cg == 0 && arow == 0) {
#pragma unroll
    for (int reg = 0; reg < 4; ++reg)
      d_lds[rg * 16 + (lane >> 4) * 4 + reg] = accd[reg];
  }
  __syncthreads();
  const size_t ob = ((size_t)b * 2048 + i0 + rg * 16) * 256 + ch * 128 + cg * 64;
#pragma unroll
  for (int reg = 0; reg < 4; ++reg) {
    int rr = (lane >> 4) * 4 + reg;
    float inv = 1.0f / d_lds[rg * 16 + rr];
#pragma unroll
    for (int ni = 0; ni < 4; ++ni) {
      int c = 16 * ni + arow;
      float v = acc[ni][reg] * inv;
      v = v > 0.f ? v : (__expf(v) - 1.f);
      out[ob + (size_t)rr * 256 + c] = v;
    }
  }
}

extern "C" void kernel_launch(void* const* d_in, const int* in_sizes, int n_in,
                              void* d_out, int out_size, void* d_ws, size_t ws_size,
                              hipStream_t stream) {
  (void)in_sizes; (void)n_in; (void)out_size;
  const float* h = (const float*)d_in[0];
  const float* W = (const float*)d_in[1];
  const float* a1 = (const float*)d_in[2];
  const float* a2 = (const float*)d_in[3];
  float* out = (float*)d_out;
  char* ws = (char*)d_ws;
  // layout (bytes)
  _Float16* Wh16 = (_Float16*)(ws);             // 8388608 (mode1: [g][c] rows; mode0: swizzled WhT)
  _Float16* W16 = (_Float16*)(ws + 8388608);    // 262144
  float* u1 = (float*)(ws + 8650752);           // 2048
  float* u2 = (float*)(ws + 8652800);           // 2048
  float* s1 = (float*)(ws + 8654848);           // 65536
  float* s2 = (float*)(ws + 8720384);           // 65536
  float* tS = (float*)(ws + 8785920);           // 65536
  int* perm = (int*)(ws + 8851456);             // 65536
  float* pp = (float*)(ws + 8916992);           // 65568
  float* pn = (float*)(ws + 8982560);           // 65568
  float* Cp = (float*)(ws + 9048128);           // 524288
  float* Cn = (float*)(ws + 9572416);           // 524288
  float* Pp = (float*)(ws + 10096704);          // 16785408
  float* Pn = (float*)(ws + 26882112);          // 16785408  -> end 43667520
  const bool big = (ws_size >= (size_t)43667520);

  hipLaunchKernelGGL(k_prologue, dim3(136), dim3(256), 0, stream, W, a1, a2, W16, u1, u2);
  hipLaunchKernelGGL(k_gemm_wh, dim3(512), dim3(256), 0, stream, h, W16, u1, u2, s1, s2,
                     Wh16, big ? 1 : 0);
  if (big) {
    hipLaunchKernelGGL(k_sort, dim3(8), dim3(512), 0, stream, s2, tS, perm);
    hipLaunchKernelGGL(k_csum, dim3(512), dim3(256), 0, stream, Wh16, tS, perm, Cp, Cn);
    hipLaunchKernelGGL(k_cscan, dim3(8), dim3(256), 0, stream, Cp, Cn);
    hipLaunchKernelGGL(k_sscan, dim3(8), dim3(256), 0, stream, tS, pp, pn);
    hipLaunchKernelGGL(k_fg, dim3(512), dim3(256), 0, stream, Wh16, tS, perm, Cp, Cn, Pp, Pn);
    hipLaunchKernelGGL(k_out, dim3(512), dim3(256), 0, stream, s1, tS, pp, pn, Pp, Pn, out);
  } else {
    hipLaunchKernelGGL(k_attn_fb, dim3(512), dim3(512), 0, stream, Wh16, s1, s2, out);
  }
}

// Round 12
// 94.086 us; speedup vs baseline: 1.2630x; 1.2630x over previous
//
#include <hip/hip_runtime.h>

typedef __attribute__((ext_vector_type(8))) _Float16 half8;
typedef __attribute__((ext_vector_type(4))) _Float16 half4;
typedef __attribute__((ext_vector_type(4))) float f32x4;
#if __has_builtin(__builtin_amdgcn_cvt_pkrtz)
typedef __attribute__((ext_vector_type(2))) __fp16 fp16x2;
#endif

#define ALPHA 0.2f
#define LOG2E 1.44269504f
#define ALC (ALPHA * LOG2E)

__device__ __forceinline__ void gload_lds16(const void* g, void* l) {
  __builtin_amdgcn_global_load_lds((const __attribute__((address_space(1))) unsigned int*)g,
                                   (__attribute__((address_space(3))) unsigned int*)l, 16, 0, 0);
}

__device__ __forceinline__ float fexp2(float x) {
#if __has_builtin(__builtin_amdgcn_exp2f)
  return __builtin_amdgcn_exp2f(x);
#else
  return exp2f(x);
#endif
}

#if __has_builtin(__builtin_amdgcn_cvt_pkrtz)
#define PACK2(DST, I, A, B)                        \
  { fp16x2 q_ = __builtin_amdgcn_cvt_pkrtz(A, B);  \
    DST[I] = (_Float16)q_[0]; DST[I + 1] = (_Float16)q_[1]; }
#else
#define PACK2(DST, I, A, B) { DST[I] = (_Float16)(A); DST[I + 1] = (_Float16)(B); }
#endif

#define EXP8(OUT, V0, V1, C1_, C2_)                                   \
  {                                                                   \
    float p0 = fexp2(fmaxf(C1_ + V0.x, fmaf(ALPHA, V0.x, C2_)));      \
    float p1 = fexp2(fmaxf(C1_ + V0.y, fmaf(ALPHA, V0.y, C2_)));      \
    float p2 = fexp2(fmaxf(C1_ + V0.z, fmaf(ALPHA, V0.z, C2_)));      \
    float p3 = fexp2(fmaxf(C1_ + V0.w, fmaf(ALPHA, V0.w, C2_)));      \
    float p4 = fexp2(fmaxf(C1_ + V1.x, fmaf(ALPHA, V1.x, C2_)));      \
    float p5 = fexp2(fmaxf(C1_ + V1.y, fmaf(ALPHA, V1.y, C2_)));      \
    float p6 = fexp2(fmaxf(C1_ + V1.z, fmaf(ALPHA, V1.z, C2_)));      \
    float p7 = fexp2(fmaxf(C1_ + V1.w, fmaf(ALPHA, V1.w, C2_)));      \
    PACK2(OUT, 0, p0, p1); PACK2(OUT, 2, p2, p3);                     \
    PACK2(OUT, 4, p4, p5); PACK2(OUT, 6, p6, p7);                     \
  }

// ---------------- K0: merged prologue — convW swizzled + uvec ----------------
__global__ __launch_bounds__(256) void k_prologue(const float* __restrict__ W,
                                                  const float* __restrict__ a1,
                                                  const float* __restrict__ a2,
                                                  _Float16* __restrict__ W16,
                                                  float* __restrict__ u1,
                                                  float* __restrict__ u2) {
  const int bid = blockIdx.x, t = threadIdx.x;
  if (bid < 128) {
    int idx4 = bid * 256 + t;
    int n = idx4 >> 7;
    int q = idx4 & 127;
    float4 v = *reinterpret_cast<const float4*>(W + n * 512 + q * 4);
    half4 hv = {(_Float16)v.x, (_Float16)v.y, (_Float16)v.z, (_Float16)v.w};
    int kp = (q * 4) ^ ((n & 7) << 3);
    *reinterpret_cast<half4*>(W16 + n * 512 + kp) = hv;
  } else {
    __shared__ float p1[4][64], p2[4][64];
    int l = t & 63, g = t >> 6;
    int k = (bid - 128) * 64 + l;
    float x1 = 0.f, x2 = 0.f;
    for (int o = g * 64; o < g * 64 + 64; ++o) {
      float wv = W[o * 512 + k];
      x1 += wv * a1[o];
      x2 += wv * a2[o];
    }
    p1[g][l] = x1; p2[g][l] = x2;
    __syncthreads();
    if (g == 0) {
      u1[k] = p1[0][l] + p1[1][l] + p1[2][l] + p1[3][l];
      u2[k] = p2[0][l] + p2[1][l] + p2[2][l] + p2[3][l];
    }
  }
}

// ---------------- K2: Wh GEMM + fused s1/s2 (R2-proven core; epilogue mode switch) ----------------
__global__ __launch_bounds__(256) void k_gemm_wh(const float* __restrict__ h,
                                                 const _Float16* __restrict__ W16,
                                                 const float* __restrict__ u1,
                                                 const float* __restrict__ u2,
                                                 float* __restrict__ s1o,
                                                 float* __restrict__ s2o,
                                                 _Float16* __restrict__ WhOut,
                                                 const int mode) {
  __shared__ _Float16 Ab[2][32 * 64];
  __shared__ _Float16 Bb[2][256 * 64];
  const int t = threadIdx.x, lane = t & 63, w = t >> 6;
  const int i0 = blockIdx.x * 32;
  const int b = i0 >> 11, n0 = i0 & 2047;
  const int ar = t >> 3, au = t & 7;
  const float* hrow = h + (size_t)(i0 + ar) * 512 + au * 8;

  f32x4 acc[2][4];
#pragma unroll
  for (int mi = 0; mi < 2; ++mi)
#pragma unroll
    for (int ni = 0; ni < 4; ++ni) acc[mi][ni] = (f32x4){0.f, 0.f, 0.f, 0.f};

  float4 aR0 = *reinterpret_cast<const float4*>(hrow);
  float4 aR1 = *reinterpret_cast<const float4*>(hrow + 4);
#pragma unroll
  for (int q = 0; q < 8; ++q) {
    int idx = (q * 4 + w) * 64 + lane;
    int nn = idx >> 3, uu = idx & 7;
    gload_lds16(W16 + nn * 512 + uu * 8, (char*)&Bb[0][0] + idx * 16);
  }
  float x1 = 0.f, x2 = 0.f;

  for (int kt = 0; kt < 8; ++kt) {
    const int cur = kt & 1;
    {
      half8 av;
      av[0] = (_Float16)aR0.x; av[1] = (_Float16)aR0.y;
      av[2] = (_Float16)aR0.z; av[3] = (_Float16)aR0.w;
      av[4] = (_Float16)aR1.x; av[5] = (_Float16)aR1.y;
      av[6] = (_Float16)aR1.z; av[7] = (_Float16)aR1.w;
      *reinterpret_cast<half8*>((char*)&Ab[cur][0] + ar * 128 + ((au * 16) ^ ((ar & 7) << 4))) = av;
      const float* up1 = u1 + kt * 64 + au * 8;
      const float* up2 = u2 + kt * 64 + au * 8;
      float4 u1a = *reinterpret_cast<const float4*>(up1);
      float4 u1b = *reinterpret_cast<const float4*>(up1 + 4);
      float4 u2a = *reinterpret_cast<const float4*>(up2);
      float4 u2b = *reinterpret_cast<const float4*>(up2 + 4);
      x1 += aR0.x * u1a.x + aR0.y * u1a.y + aR0.z * u1a.z + aR0.w * u1a.w
          + aR1.x * u1b.x + aR1.y * u1b.y + aR1.z * u1b.z + aR1.w * u1b.w;
      x2 += aR0.x * u2a.x + aR0.y * u2a.y + aR0.z * u2a.z + aR0.w * u2a.w
          + aR1.x * u2b.x + aR1.y * u2b.y + aR1.z * u2b.z + aR1.w * u2b.w;
    }
    __syncthreads();
    if (kt < 7) {
      const int k0 = (kt + 1) * 64;
      aR0 = *reinterpret_cast<const float4*>(hrow + k0);
      aR1 = *reinterpret_cast<const float4*>(hrow + k0 + 4);
#pragma unroll
      for (int q = 0; q < 8; ++q) {
        int idx = (q * 4 + w) * 64 + lane;
        int nn = idx >> 3, uu = idx & 7;
        gload_lds16(W16 + nn * 512 + k0 + uu * 8, (char*)&Bb[cur ^ 1][0] + idx * 16);
      }
    }
    const char* Ac = (const char*)&Ab[cur][0];
    const char* Bc = (const char*)&Bb[cur][0];
#pragma unroll
    for (int kk = 0; kk < 2; ++kk) {
      const int jb = (lane >> 4) * 16 + kk * 64;
      half8 afr[2];
#pragma unroll
      for (int mi = 0; mi < 2; ++mi) {
        int rr = (lane & 15) + 16 * mi;
        afr[mi] = *reinterpret_cast<const half8*>(Ac + rr * 128 + (jb ^ ((rr & 7) << 4)));
      }
#pragma unroll
      for (int ni = 0; ni < 4; ++ni) {
        int nn = 64 * w + 16 * ni + (lane & 15);
        half8 bfr = *reinterpret_cast<const half8*>(Bc + nn * 128 + (jb ^ ((nn & 7) << 4)));
#pragma unroll
        for (int mi = 0; mi < 2; ++mi)
          acc[mi][ni] = __builtin_amdgcn_mfma_f32_16x16x32_f16(afr[mi], bfr, acc[mi][ni], 0, 0, 0);
      }
    }
  }
  x1 += __shfl_xor(x1, 1); x1 += __shfl_xor(x1, 2); x1 += __shfl_xor(x1, 4);
  x2 += __shfl_xor(x2, 1); x2 += __shfl_xor(x2, 2); x2 += __shfl_xor(x2, 4);
  if (au == 0) { s1o[i0 + ar] = x1; s2o[i0 + ar] = x2; }
  if (mode) {
#pragma unroll
    for (int mi = 0; mi < 2; ++mi)
#pragma unroll
      for (int ni = 0; ni < 4; ++ni) {
        int c = 64 * w + 16 * ni + (lane & 15);
        int g = i0 + 16 * mi + (lane >> 4) * 4;
        f32x4 a = acc[mi][ni];
#pragma unroll
        for (int reg = 0; reg < 4; ++reg)
          WhOut[(size_t)(g + reg) * 256 + c] = (_Float16)a[reg];
      }
  } else {
    _Float16* whtb = WhOut + (size_t)b * 256 * 2048;
#pragma unroll
    for (int mi = 0; mi < 2; ++mi)
#pragma unroll
      for (int ni = 0; ni < 4; ++ni) {
        int c = 64 * w + 16 * ni + (lane & 15);
        int nb = n0 + 16 * mi + (lane >> 4) * 4;
        int np = nb ^ ((c & 7) << 3);
        f32x4 a = acc[mi][ni];
        half4 hv = {(_Float16)a[0], (_Float16)a[1], (_Float16)a[2], (_Float16)a[3]};
        *reinterpret_cast<half4*>(whtb + (size_t)c * 2048 + np) = hv;
      }
  }
}

// ---------------- K3: rank-by-count sort replacement ----------------
// 64 blocks (b*8+g) x 512 thr: two threads per j (each counts half the range),
// strict total order via index tiebreak; scatter tS[rank]=v, perm[rank]=j.
__global__ __launch_bounds__(512) void k_rank(const float* __restrict__ s2,
                                              float* __restrict__ tS,
                                              int* __restrict__ perm) {
  __shared__ float sv[2048];
  __shared__ int partial[256];
  const int bid = blockIdx.x;
  const int b = bid >> 3, g = bid & 7;
  const int t = threadIdx.x;
  for (int i = t; i < 2048; i += 512) sv[i] = s2[b * 2048 + i];
  __syncthreads();
  const int tj = t & 255, half = t >> 8;
  const int j = g * 256 + tj;
  const float v = sv[j];
  int rank = 0;
  const int r0 = half * 1024;
  for (int r = r0; r < r0 + 1024; r += 4) {
    float4 q = *reinterpret_cast<const float4*>(&sv[r]);  // uniform addr -> broadcast
    rank += (q.x < v || (q.x == v && (r + 0) < j)) ? 1 : 0;
    rank += (q.y < v || (q.y == v && (r + 1) < j)) ? 1 : 0;
    rank += (q.z < v || (q.z == v && (r + 2) < j)) ? 1 : 0;
    rank += (q.w < v || (q.w == v && (r + 3) < j)) ? 1 : 0;
  }
  if (half) partial[tj] = rank;
  __syncthreads();
  if (!half) {
    int rk = rank + partial[tj];
    tS[b * 2048 + rk] = v;
    perm[b * 2048 + rk] = j;
  }
}

// ---------------- K4: chunk sums (32 sorted rows per chunk) ----------------
__global__ __launch_bounds__(256) void k_csum(const _Float16* __restrict__ Wh16,
                                              const float* __restrict__ tS,
                                              const int* __restrict__ perm,
                                              float* __restrict__ Cp,
                                              float* __restrict__ Cn) {
  const int bid = blockIdx.x;  // b*64 + ch
  const int b = bid >> 6, ch = bid & 63, t = threadIdx.x;
  const int base = b * 2048 + ch * 32;
  float rp = 0.f, rn = 0.f;
  for (int r = 0; r < 32; ++r) {
    int row = perm[base + r];
    float tv = tS[base + r];
    float wp = fexp2(LOG2E * tv);
    float wn = fexp2(ALC * tv);
    float v = (float)Wh16[((size_t)b * 2048 + row) * 256 + t];
    rp = fmaf(wp, v, rp);
    rn = fmaf(wn, v, rn);
  }
  Cp[(size_t)bid * 256 + t] = rp;
  Cn[(size_t)bid * 256 + t] = rn;
}

// ---------------- K5: fused scans — blocks 0..15: chunk-scan in LDS; 16..23: scalar scan ----------------
__global__ __launch_bounds__(256) void k_scans(const float* __restrict__ tS,
                                               float* __restrict__ Cp,
                                               float* __restrict__ Cn,
                                               float* __restrict__ pp,
                                               float* __restrict__ pn) {
  const int bid = blockIdx.x, t = threadIdx.x;
  if (bid < 16) {
    // exclusive scan over 64 chunks, per (batch=bid>>1, col-half=bid&1, 128 cols)
    __shared__ float S[2][64][128];
    const int b = bid >> 1, hf = bid & 1;
    for (int i = t; i < 8192; i += 256) {
      int ch = i >> 7, col = i & 127;
      size_t o = ((size_t)(b * 64 + ch)) * 256 + hf * 128 + col;
      S[0][ch][col] = Cp[o];
      S[1][ch][col] = Cn[o];
    }
    __syncthreads();
    {
      const int a = t >> 7, col = t & 127;  // t<128: Cp col; t>=128: Cn col
      float acc = 0.f;
      for (int ch = 0; ch < 64; ++ch) {
        float x = S[a][ch][col];
        S[a][ch][col] = acc;
        acc += x;
      }
    }
    __syncthreads();
    for (int i = t; i < 8192; i += 256) {
      int ch = i >> 7, col = i & 127;
      size_t o = ((size_t)(b * 64 + ch)) * 256 + hf * 128 + col;
      Cp[o] = S[0][ch][col];
      Cn[o] = S[1][ch][col];
    }
  } else {
    // scalar weight prefix sums pp/pn[0..2048] for batch b = bid-16 (Hillis-Steele)
    __shared__ float SA[256], SB[256];
    const int b = bid - 16;
    float lp[8], ln[8];
    float ap = 0.f, an = 0.f;
#pragma unroll
    for (int x = 0; x < 8; ++x) {
      float tv = tS[b * 2048 + t * 8 + x];
      lp[x] = ap; ln[x] = an;
      ap += fexp2(LOG2E * tv);
      an += fexp2(ALC * tv);
    }
    SA[t] = ap; SB[t] = an;
    __syncthreads();
    for (int off = 1; off < 256; off <<= 1) {
      float xp = (t >= off) ? SA[t - off] : 0.f;
      float xn = (t >= off) ? SB[t - off] : 0.f;
      __syncthreads();
      SA[t] += xp; SB[t] += xn;
      __syncthreads();
    }
    float bp = (t == 0) ? 0.f : SA[t - 1];
    float bn = (t == 0) ? 0.f : SB[t - 1];
#pragma unroll
    for (int x = 0; x < 8; ++x) {
      pp[b * 2049 + t * 8 + x] = bp + lp[x];
      pn[b * 2049 + t * 8 + x] = bn + ln[x];
    }
    if (t == 255) {
      pp[b * 2049 + 2048] = SA[255];
      pn[b * 2049 + 2048] = SB[255];
    }
  }
}

// ---------------- K6: write exclusive prefix arrays Pp/Pn[k][c] ----------------
__global__ __launch_bounds__(256) void k_fg(const _Float16* __restrict__ Wh16,
                                            const float* __restrict__ tS,
                                            const int* __restrict__ perm,
                                            const float* __restrict__ Cp,
                                            const float* __restrict__ Cn,
                                            float* __restrict__ Pp,
                                            float* __restrict__ Pn) {
  const int bid = blockIdx.x;
  const int b = bid >> 6, ch = bid & 63, t = threadIdx.x;
  const int base = b * 2048 + ch * 32;
  float rp = Cp[(size_t)bid * 256 + t];
  float rn = Cn[(size_t)bid * 256 + t];
  for (int r = 0; r < 32; ++r) {
    int k = ch * 32 + r;
    size_t po = ((size_t)b * 2049 + k) * 256 + t;
    Pp[po] = rp; Pn[po] = rn;
    int row = perm[base + r];
    float tv = tS[base + r];
    float wp = fexp2(LOG2E * tv);
    float wn = fexp2(ALC * tv);
    float v = (float)Wh16[((size_t)b * 2048 + row) * 256 + t];
    rp = fmaf(wp, v, rp);
    rn = fmaf(wn, v, rn);
  }
  if (ch == 63) {
    size_t po = ((size_t)b * 2049 + 2048) * 256 + t;
    Pp[po] = rp; Pn[po] = rn;
  }
}

// ---------------- K7: output — binary search + combine + ELU ----------------
__global__ __launch_bounds__(256) void k_out(const float* __restrict__ s1,
                                             const float* __restrict__ tS,
                                             const float* __restrict__ pp,
                                             const float* __restrict__ pn,
                                             const float* __restrict__ Pp,
                                             const float* __restrict__ Pn,
                                             float* __restrict__ out) {
  __shared__ float tSh[2048];
  __shared__ float pps[2049], pns[2049];
  const int bid = blockIdx.x;
  const int b = bid & 7, grp = bid >> 3;
  const int t = threadIdx.x;
  for (int i = t; i < 2048; i += 256) tSh[i] = tS[b * 2048 + i];
  for (int i = t; i < 2049; i += 256) { pps[i] = pp[b * 2049 + i]; pns[i] = pn[b * 2049 + i]; }
  __syncthreads();
  const int rl = t >> 3, q = t & 7;
  const int i = grp * 32 + rl;
  const float s1v = s1[b * 2048 + i];
  const float tmax = tSh[2047];
  const float e0 = s1v + tmax;
  const float m = fmaxf(e0, ALPHA * e0);
  const float A = fexp2(LOG2E * (s1v - m));
  const float B = fexp2(LOG2E * fmaf(ALPHA, s1v, -m));
  const float thr = -s1v;
  int k = 0;
#pragma unroll
  for (int s = 2048; s >= 1; s >>= 1) {
    int nk = k + s;
    if (nk <= 2048 && tSh[nk - 1] <= thr) k = nk;
  }
  const float d = B * pns[k] + A * (pps[2048] - pps[k]);
  const float inv = 1.0f / d;
  const float4* fp4 = (const float4*)(Pp + ((size_t)b * 2049 + k) * 256);
  const float4* fn4 = (const float4*)(Pn + ((size_t)b * 2049 + k) * 256);
  const float4* tt4 = (const float4*)(Pp + ((size_t)b * 2049 + 2048) * 256);
  float4* op = (float4*)(out + ((size_t)b * 2048 + i) * 256);
#pragma unroll
  for (int x = 0; x < 8; ++x) {
    int c4 = x * 8 + q;
    float4 fp = fp4[c4], fn = fn4[c4], tt = tt4[c4];
    float4 v;
    v.x = (B * fn.x + A * (tt.x - fp.x)) * inv;
    v.y = (B * fn.y + A * (tt.y - fp.y)) * inv;
    v.z = (B * fn.z + A * (tt.z - fp.z)) * inv;
    v.w = (B * fn.w + A * (tt.w - fp.w)) * inv;
    v.x = v.x > 0.f ? v.x : (__expf(v.x) - 1.f);
    v.y = v.y > 0.f ? v.y : (__expf(v.y) - 1.f);
    v.z = v.z > 0.f ? v.z : (__expf(v.z) - 1.f);
    v.w = v.w > 0.f ? v.w : (__expf(v.w) - 1.f);
    op[c4] = v;
  }
}

// ---------------- FALLBACK attn (R10-proven, used when ws too small) ----------------
__global__ __launch_bounds__(512) void k_attn_fb(const _Float16* __restrict__ WhT,
                                                 const float* __restrict__ s1,
                                                 const float* __restrict__ s2,
                                                 float* __restrict__ out) {
  __shared__ _Float16 Bb[3][128 * 64];
  __shared__ _Float16 Pb[2][64 * 64];
  __shared__ float s2s[2048];
  __shared__ float red[8];
  __shared__ float d_lds[64];
  const int t = threadIdx.x, lane = t & 63, w = t >> 6;
  const int rg = w >> 1, cg = w & 1;
  const int b = blockIdx.x & 7;
  const int i0 = ((blockIdx.x >> 3) & 31) * 64;
  const int ch = blockIdx.x >> 8;
  const _Float16* whtb = WhT + ((size_t)b * 256 + ch * 128) * 2048;
  const int arow = lane & 15;
  const int pr = t >> 3, pj8 = t & 7;
  const float s1v = s1[b * 2048 + i0 + pr];

  float4 sv4 = *reinterpret_cast<const float4*>(s2 + b * 2048 + t * 4);
  float m0 = fmaxf(fmaxf(sv4.x, sv4.y), fmaxf(sv4.z, sv4.w));
  *reinterpret_cast<float4*>(&s2s[t * 4]) =
      make_float4(sv4.x * LOG2E, sv4.y * LOG2E, sv4.z * LOG2E, sv4.w * LOG2E);
#pragma unroll
  for (int off = 32; off >= 1; off >>= 1) m0 = fmaxf(m0, __shfl_xor(m0, off));
  if (lane == 0) red[w] = m0;
  __syncthreads();
  float smaxL;
  {
    float mm = fmaxf(fmaxf(red[0], red[1]), fmaxf(red[2], red[3]));
    mm = fmaxf(mm, fmaxf(fmaxf(red[4], red[5]), fmaxf(red[6], red[7])));
    smaxL = mm * LOG2E;
  }
  const float s1L = LOG2E * s1v;
  const float e0L = s1L + smaxL;
  const float mrowL = fmaxf(e0L, ALPHA * e0L);
  const float C1 = s1L - mrowL;
  const float C2 = fmaf(ALPHA, s1L, -mrowL);
  const int pwoff = pr * 128 + ((pj8 * 16) ^ ((pr & 7) << 4));
  half8 onesb;
  {
    _Float16 ov = (arow == 0) ? (_Float16)1.0f : (_Float16)0.0f;
#pragma unroll
    for (int x = 0; x < 8; ++x) onesb[x] = ov;
  }
  f32x4 acc[4];
#pragma unroll
  for (int ni = 0; ni < 4; ++ni) acc[ni] = (f32x4){0.f, 0.f, 0.f, 0.f};
  f32x4 accd = (f32x4){0.f, 0.f, 0.f, 0.f};
  {
    const float* sp = &s2s[pj8 * 8];
    float4 v0 = *reinterpret_cast<const float4*>(sp);
    float4 v1 = *reinterpret_cast<const float4*>(sp + 4);
    half8 ph;
    EXP8(ph, v0, v1, C1, C2);
    *reinterpret_cast<half8*>((char*)&Pb[0][0] + pwoff) = ph;
  }
#pragma unroll
  for (int x = 0; x < 2; ++x)
#pragma unroll
    for (int q = 0; q < 2; ++q) {
      int idx = q * 512 + t;
      int cl = idx >> 3, uu = idx & 7;
      gload_lds16(whtb + (size_t)cl * 2048 + x * 64 + uu * 8, (char*)&Bb[x][0] + idx * 16);
    }
  for (int jt = 0; jt < 32; ++jt) {
    if (jt < 31) asm volatile("s_waitcnt vmcnt(2) lgkmcnt(0)" ::: "memory");
    else         asm volatile("s_waitcnt vmcnt(0) lgkmcnt(0)" ::: "memory");
    __builtin_amdgcn_s_barrier();
    if (jt < 30) {
      const int j0n = (jt + 2) * 64;
      const int p = (jt + 2) % 3;
#pragma unroll
      for (int q = 0; q < 2; ++q) {
        int idx = q * 512 + t;
        int cl = idx >> 3, uu = idx & 7;
        gload_lds16(whtb + (size_t)cl * 2048 + j0n + uu * 8, (char*)&Bb[p][0] + idx * 16);
      }
    }
    if (jt < 31) {
      const float* sp = &s2s[(jt + 1) * 64 + pj8 * 8];
      float4 v0 = *reinterpret_cast<const float4*>(sp);
      float4 v1 = *reinterpret_cast<const float4*>(sp + 4);
      half8 ph;
      EXP8(ph, v0, v1, C1, C2);
      *reinterpret_cast<half8*>((char*)&Pb[(jt + 1) & 1][0] + pwoff) = ph;
    }
    const char* Bc = (const char*)&Bb[jt % 3][0];
    const char* Pc = (const char*)&Pb[jt & 1][0];
#pragma unroll
    for (int kk = 0; kk < 2; ++kk) {
      const int jb = ((lane >> 4) * 8 + kk * 32) * 2;
      const int ar64 = rg * 16 + arow;
      half8 afr = *reinterpret_cast<const half8*>(Pc + ar64 * 128 + (jb ^ ((ar64 & 7) << 4)));
      if (cg == 0)
        accd = __builtin_amdgcn_mfma_f32_16x16x32_f16(afr, onesb, accd, 0, 0, 0);
#pragma unroll
      for (int ni = 0; ni < 4; ++ni) {
        int cl = cg * 64 + 16 * ni + arow;
        half8 bfr = *reinterpret_cast<const half8*>(Bc + cl * 128 + (jb ^ ((cl & 7) << 4)));
        acc[ni] = __builtin_amdgcn_mfma_f32_16x16x32_f16(afr, bfr, acc[ni], 0, 0, 0);
      }
    }
  }
  if (cg == 0 && arow == 0) {
#pragma unroll
    for (int reg = 0; reg < 4; ++reg)
      d_lds[rg * 16 + (lane >> 4) * 4 + reg] = accd[reg];
  }
  __syncthreads();
  const size_t ob = ((size_t)b * 2048 + i0 + rg * 16) * 256 + ch * 128 + cg * 64;
#pragma unroll
  for (int reg = 0; reg < 4; ++reg) {
    int rr = (lane >> 4) * 4 + reg;
    float inv = 1.0f / d_lds[rg * 16 + rr];
#pragma unroll
    for (int ni = 0; ni < 4; ++ni) {
      int c = 16 * ni + arow;
      float v = acc[ni][reg] * inv;
      v = v > 0.f ? v : (__expf(v) - 1.f);
      out[ob + (size_t)rr * 256 + c] = v;
    }
  }
}

extern "C" void kernel_launch(void* const* d_in, const int* in_sizes, int n_in,
                              void* d_out, int out_size, void* d_ws, size_t ws_size,
                              hipStream_t stream) {
  (void)in_sizes; (void)n_in; (void)out_size;
  const float* h = (const float*)d_in[0];
  const float* W = (const float*)d_in[1];
  const float* a1 = (const float*)d_in[2];
  const float* a2 = (const float*)d_in[3];
  float* out = (float*)d_out;
  char* ws = (char*)d_ws;
  _Float16* Wh16 = (_Float16*)(ws);             // 8388608
  _Float16* W16 = (_Float16*)(ws + 8388608);    // 262144
  float* u1 = (float*)(ws + 8650752);           // 2048
  float* u2 = (float*)(ws + 8652800);           // 2048
  float* s1 = (float*)(ws + 8654848);           // 65536
  float* s2 = (float*)(ws + 8720384);           // 65536
  float* tS = (float*)(ws + 8785920);           // 65536
  int* perm = (int*)(ws + 8851456);             // 65536
  float* pp = (float*)(ws + 8916992);           // 65568
  float* pn = (float*)(ws + 8982560);           // 65568
  float* Cp = (float*)(ws + 9048128);           // 524288
  float* Cn = (float*)(ws + 9572416);           // 524288
  float* Pp = (float*)(ws + 10096704);          // 16785408
  float* Pn = (float*)(ws + 26882112);          // 16785408  -> end 43667520
  const bool big = (ws_size >= (size_t)43667520);

  hipLaunchKernelGGL(k_prologue, dim3(136), dim3(256), 0, stream, W, a1, a2, W16, u1, u2);
  hipLaunchKernelGGL(k_gemm_wh, dim3(512), dim3(256), 0, stream, h, W16, u1, u2, s1, s2,
                     Wh16, big ? 1 : 0);
  if (big) {
    hipLaunchKernelGGL(k_rank, dim3(64), dim3(512), 0, stream, s2, tS, perm);
    hipLaunchKernelGGL(k_csum, dim3(512), dim3(256), 0, stream, Wh16, tS, perm, Cp, Cn);
    hipLaunchKernelGGL(k_scans, dim3(24), dim3(256), 0, stream, tS, Cp, Cn, pp, pn);
    hipLaunchKernelGGL(k_fg, dim3(512), dim3(256), 0, stream, Wh16, tS, perm, Cp, Cn, Pp, Pn);
    hipLaunchKernelGGL(k_out, dim3(512), dim3(256), 0, stream, s1, tS, pp, pn, Pp, Pn, out);
  } else {
    hipLaunchKernelGGL(k_attn_fb, dim3(512), dim3(512), 0, stream, Wh16, s1, s2, out);
  }
}

// Round 13
// 66.914 us; speedup vs baseline: 1.7759x; 1.4061x over previous
//
#include <hip/hip_runtime.h>

typedef __attribute__((ext_vector_type(8))) _Float16 half8;
typedef __attribute__((ext_vector_type(4))) _Float16 half4;
typedef __attribute__((ext_vector_type(4))) float f32x4;
#if __has_builtin(__builtin_amdgcn_cvt_pkrtz)
typedef __attribute__((ext_vector_type(2))) __fp16 fp16x2;
#endif

#define ALPHA 0.2f
#define LOG2E 1.44269504f

__device__ __forceinline__ void gload_lds16(const void* g, void* l) {
  __builtin_amdgcn_global_load_lds((const __attribute__((address_space(1))) unsigned int*)g,
                                   (__attribute__((address_space(3))) unsigned int*)l, 16, 0, 0);
}

__device__ __forceinline__ float fexp2(float x) {
#if __has_builtin(__builtin_amdgcn_exp2f)
  return __builtin_amdgcn_exp2f(x);
#else
  return exp2f(x);
#endif
}

#if __has_builtin(__builtin_amdgcn_cvt_pkrtz)
#define PACK2(DST, I, A, B)                        \
  { fp16x2 q_ = __builtin_amdgcn_cvt_pkrtz(A, B);  \
    DST[I] = (_Float16)q_[0]; DST[I + 1] = (_Float16)q_[1]; }
#else
#define PACK2(DST, I, A, B) { DST[I] = (_Float16)(A); DST[I + 1] = (_Float16)(B); }
#endif

// EXP8: one half8 (8 consecutive j) of P for one row
#define EXP8(OUT, V0, V1, C1_, C2_)                                   \
  {                                                                   \
    float p0 = fexp2(fmaxf(C1_ + V0.x, fmaf(ALPHA, V0.x, C2_)));      \
    float p1 = fexp2(fmaxf(C1_ + V0.y, fmaf(ALPHA, V0.y, C2_)));      \
    float p2 = fexp2(fmaxf(C1_ + V0.z, fmaf(ALPHA, V0.z, C2_)));      \
    float p3 = fexp2(fmaxf(C1_ + V0.w, fmaf(ALPHA, V0.w, C2_)));      \
    float p4 = fexp2(fmaxf(C1_ + V1.x, fmaf(ALPHA, V1.x, C2_)));      \
    float p5 = fexp2(fmaxf(C1_ + V1.y, fmaf(ALPHA, V1.y, C2_)));      \
    float p6 = fexp2(fmaxf(C1_ + V1.z, fmaf(ALPHA, V1.z, C2_)));      \
    float p7 = fexp2(fmaxf(C1_ + V1.w, fmaf(ALPHA, V1.w, C2_)));      \
    PACK2(OUT, 0, p0, p1); PACK2(OUT, 2, p2, p3);                     \
    PACK2(OUT, 4, p4, p5); PACK2(OUT, 6, p6, p7);                     \
  }

// ---------------- K0: merged prologue — convW (blocks 0..127) + uvec (blocks 128..135) ----------------
__global__ __launch_bounds__(256) void k_prologue(const float* __restrict__ W,
                                                  const float* __restrict__ a1,
                                                  const float* __restrict__ a2,
                                                  _Float16* __restrict__ W16,
                                                  float* __restrict__ u1,
                                                  float* __restrict__ u2) {
  const int bid = blockIdx.x, t = threadIdx.x;
  if (bid < 128) {
    // W fp32 -> fp16, PRE-SWIZZLED (unit8 XOR (n&7))
    int idx4 = bid * 256 + t;
    int n = idx4 >> 7;
    int q = idx4 & 127;
    float4 v = *reinterpret_cast<const float4*>(W + n * 512 + q * 4);
    half4 hv = {(_Float16)v.x, (_Float16)v.y, (_Float16)v.z, (_Float16)v.w};
    int kp = (q * 4) ^ ((n & 7) << 3);
    *reinterpret_cast<half4*>(W16 + n * 512 + kp) = hv;
  } else {
    // u = W^T a (coalesced over k)
    __shared__ float p1[4][64], p2[4][64];
    int l = t & 63, g = t >> 6;
    int k = (bid - 128) * 64 + l;
    float x1 = 0.f, x2 = 0.f;
    for (int o = g * 64; o < g * 64 + 64; ++o) {
      float wv = W[o * 512 + k];
      x1 += wv * a1[o];
      x2 += wv * a2[o];
    }
    p1[g][l] = x1; p2[g][l] = x2;
    __syncthreads();
    if (g == 0) {
      u1[k] = p1[0][l] + p1[1][l] + p1[2][l] + p1[3][l];
      u2[k] = p2[0][l] + p2[1][l] + p2[2][l] + p2[3][l];
    }
  }
}

// ---------------- K2: Wh GEMM + fused s1/s2 (R2-proven structure, do not touch) ----------------
// block: 32 rows x 256 cols, 4 waves (each 32x64), 512 blocks (2/CU)
__global__ __launch_bounds__(256) void k_gemm_wh(const float* __restrict__ h,
                                                 const _Float16* __restrict__ W16,
                                                 const float* __restrict__ u1,
                                                 const float* __restrict__ u2,
                                                 float* __restrict__ s1o,
                                                 float* __restrict__ s2o,
                                                 _Float16* __restrict__ WhT) {
  __shared__ _Float16 Ab[2][32 * 64];    // 4 KB each, swizzled (reg-staged)
  __shared__ _Float16 Bb[2][256 * 64];   // 32 KB each, linear copy of pre-swizzled W16
  const int t = threadIdx.x, lane = t & 63, w = t >> 6;
  const int i0 = blockIdx.x * 32;        // global row 0..16383
  const int b = i0 >> 11, n0 = i0 & 2047;
  const int ar = t >> 3, au = t & 7;     // A-stage: row 0..31, 8-float chunk 0..7
  const float* hrow = h + (size_t)(i0 + ar) * 512 + au * 8;

  f32x4 acc[2][4];
#pragma unroll
  for (int mi = 0; mi < 2; ++mi)
#pragma unroll
    for (int ni = 0; ni < 4; ++ni) acc[mi][ni] = (f32x4){0.f, 0.f, 0.f, 0.f};

  // prologue: load A(0) regs, stage B(0) via global_load_lds
  float4 aR0 = *reinterpret_cast<const float4*>(hrow);
  float4 aR1 = *reinterpret_cast<const float4*>(hrow + 4);
#pragma unroll
  for (int q = 0; q < 8; ++q) {
    int idx = (q * 4 + w) * 64 + lane;
    int nn = idx >> 3, uu = idx & 7;
    gload_lds16(W16 + nn * 512 + uu * 8, (char*)&Bb[0][0] + idx * 16);
  }
  float x1 = 0.f, x2 = 0.f;

  for (int kt = 0; kt < 8; ++kt) {
    const int cur = kt & 1;
    // ds_write A(kt) (+ fused s1/s2 partials on the same registers)
    {
      half8 av;
      av[0] = (_Float16)aR0.x; av[1] = (_Float16)aR0.y;
      av[2] = (_Float16)aR0.z; av[3] = (_Float16)aR0.w;
      av[4] = (_Float16)aR1.x; av[5] = (_Float16)aR1.y;
      av[6] = (_Float16)aR1.z; av[7] = (_Float16)aR1.w;
      *reinterpret_cast<half8*>((char*)&Ab[cur][0] + ar * 128 + ((au * 16) ^ ((ar & 7) << 4))) = av;
      const float* up1 = u1 + kt * 64 + au * 8;
      const float* up2 = u2 + kt * 64 + au * 8;
      float4 u1a = *reinterpret_cast<const float4*>(up1);
      float4 u1b = *reinterpret_cast<const float4*>(up1 + 4);
      float4 u2a = *reinterpret_cast<const float4*>(up2);
      float4 u2b = *reinterpret_cast<const float4*>(up2 + 4);
      x1 += aR0.x * u1a.x + aR0.y * u1a.y + aR0.z * u1a.z + aR0.w * u1a.w
          + aR1.x * u1b.x + aR1.y * u1b.y + aR1.z * u1b.z + aR1.w * u1b.w;
      x2 += aR0.x * u2a.x + aR0.y * u2a.y + aR0.z * u2a.z + aR0.w * u2a.w
          + aR1.x * u2b.x + aR1.y * u2b.y + aR1.z * u2b.z + aR1.w * u2b.w;
    }
    __syncthreads();  // A(kt) visible; B(kt) loads drained
    if (kt < 7) {     // prefetch tile kt+1 (lands during compute below)
      const int k0 = (kt + 1) * 64;
      aR0 = *reinterpret_cast<const float4*>(hrow + k0);
      aR1 = *reinterpret_cast<const float4*>(hrow + k0 + 4);
#pragma unroll
      for (int q = 0; q < 8; ++q) {
        int idx = (q * 4 + w) * 64 + lane;
        int nn = idx >> 3, uu = idx & 7;
        gload_lds16(W16 + nn * 512 + k0 + uu * 8, (char*)&Bb[cur ^ 1][0] + idx * 16);
      }
    }
    // compute tile kt
    const char* Ac = (const char*)&Ab[cur][0];
    const char* Bc = (const char*)&Bb[cur][0];
#pragma unroll
    for (int kk = 0; kk < 2; ++kk) {
      const int jb = (lane >> 4) * 16 + kk * 64;
      half8 afr[2];
#pragma unroll
      for (int mi = 0; mi < 2; ++mi) {
        int rr = (lane & 15) + 16 * mi;
        afr[mi] = *reinterpret_cast<const half8*>(Ac + rr * 128 + (jb ^ ((rr & 7) << 4)));
      }
#pragma unroll
      for (int ni = 0; ni < 4; ++ni) {
        int nn = 64 * w + 16 * ni + (lane & 15);
        half8 bfr = *reinterpret_cast<const half8*>(Bc + nn * 128 + (jb ^ ((nn & 7) << 4)));
#pragma unroll
        for (int mi = 0; mi < 2; ++mi)
          acc[mi][ni] = __builtin_amdgcn_mfma_f32_16x16x32_f16(afr[mi], bfr, acc[mi][ni], 0, 0, 0);
      }
    }
  }
  // s1/s2: reduce over the 8 threads sharing a row (contiguous lanes)
  x1 += __shfl_xor(x1, 1); x1 += __shfl_xor(x1, 2); x1 += __shfl_xor(x1, 4);
  x2 += __shfl_xor(x2, 1); x2 += __shfl_xor(x2, 2); x2 += __shfl_xor(x2, 4);
  if (au == 0) { s1o[i0 + ar] = x1; s2o[i0 + ar] = x2; }
  // epilogue: pre-swizzled WhT store (unit8 XOR (c&7), within 64-n blocks)
  _Float16* whtb = WhT + (size_t)b * 256 * 2048;
#pragma unroll
  for (int mi = 0; mi < 2; ++mi)
#pragma unroll
    for (int ni = 0; ni < 4; ++ni) {
      int c = 64 * w + 16 * ni + (lane & 15);
      int nb = n0 + 16 * mi + (lane >> 4) * 4;
      int np = nb ^ ((c & 7) << 3);
      f32x4 a = acc[mi][ni];
      half4 hv = {(_Float16)a[0], (_Float16)a[1], (_Float16)a[2], (_Float16)a[3]};
      *reinterpret_cast<half4*>(whtb + (size_t)c * 2048 + np) = hv;
    }
}

// ---------------- K3: fused softmax(P) @ Wh + ELU — R10-proven structure + T5 setprio ----------------
// grid 512 (bid&7 = batch -> XCD affinity; (bid>>3)&31 = 64-row block; bid>>8 = col half),
// 512 thr = 8 waves (4 rg x 2 cg), wave = 16 rows x 64 cols. Block covers 64 rows x 128 cols.
// B triple-buffered (16 KB tiles), P (64x64) double-buffered, s2 staged+scaled in LDS,
// per-batch max in-block. Counted vmcnt(2): loads span the single per-tile barrier (T3+T4).
// NEW vs R10: s_setprio(1) around the MFMA cluster (T5; attn-positive per m191).
__global__ __launch_bounds__(512) void k_attn(const _Float16* __restrict__ WhT,
                                              const float* __restrict__ s1,
                                              const float* __restrict__ s2,
                                              float* __restrict__ out) {
  __shared__ _Float16 Bb[3][128 * 64];  // 16 KB each
  __shared__ _Float16 Pb[2][64 * 64];   // 8 KB each
  __shared__ float s2s[2048];
  __shared__ float red[8];
  __shared__ float d_lds[64];
  const int t = threadIdx.x, lane = t & 63, w = t >> 6;
  const int rg = w >> 1, cg = w & 1;
  const int b = blockIdx.x & 7;
  const int i0 = ((blockIdx.x >> 3) & 31) * 64;
  const int ch = blockIdx.x >> 8;          // column half 0/1
  const _Float16* whtb = WhT + ((size_t)b * 256 + ch * 128) * 2048;
  const int arow = lane & 15;
  const int pr = t >> 3, pj8 = t & 7;      // P-build: row 0..63, 8-j chunk 0..7
  const float s1v = s1[b * 2048 + i0 + pr];

  // stage s2 (scaled by log2e) + block-wide max
  float4 sv4 = *reinterpret_cast<const float4*>(s2 + b * 2048 + t * 4);
  float m0 = fmaxf(fmaxf(sv4.x, sv4.y), fmaxf(sv4.z, sv4.w));
  *reinterpret_cast<float4*>(&s2s[t * 4]) =
      make_float4(sv4.x * LOG2E, sv4.y * LOG2E, sv4.z * LOG2E, sv4.w * LOG2E);
#pragma unroll
  for (int off = 32; off >= 1; off >>= 1) m0 = fmaxf(m0, __shfl_xor(m0, off));
  if (lane == 0) red[w] = m0;
  __syncthreads();  // full drain: clean vmcnt slate; s2s/red visible
  float smaxL;
  {
    float mm = fmaxf(fmaxf(red[0], red[1]), fmaxf(red[2], red[3]));
    mm = fmaxf(mm, fmaxf(fmaxf(red[4], red[5]), fmaxf(red[6], red[7])));
    smaxL = mm * LOG2E;
  }
  const float s1L = LOG2E * s1v;
  const float e0L = s1L + smaxL;
  const float mrowL = fmaxf(e0L, ALPHA * e0L);  // closed-form row max (LR monotonic)
  const float C1 = s1L - mrowL;
  const float C2 = fmaf(ALPHA, s1L, -mrowL);
  const int pwoff = pr * 128 + ((pj8 * 16) ^ ((pr & 7) << 4));
  half8 onesb;
  {
    _Float16 ov = (arow == 0) ? (_Float16)1.0f : (_Float16)0.0f;
#pragma unroll
    for (int x = 0; x < 8; ++x) onesb[x] = ov;
  }
  f32x4 acc[4];
#pragma unroll
  for (int ni = 0; ni < 4; ++ni) acc[ni] = (f32x4){0.f, 0.f, 0.f, 0.f};
  f32x4 accd = (f32x4){0.f, 0.f, 0.f, 0.f};

  // build P(0)
  {
    const float* sp = &s2s[pj8 * 8];
    float4 v0 = *reinterpret_cast<const float4*>(sp);
    float4 v1 = *reinterpret_cast<const float4*>(sp + 4);
    half8 ph;
    EXP8(ph, v0, v1, C1, C2);
    *reinterpret_cast<half8*>((char*)&Pb[0][0] + pwoff) = ph;
  }
  // issue B(0), B(1): 2 gload_lds per thread per tile (16 KB / 512 thr / 16 B)
#pragma unroll
  for (int x = 0; x < 2; ++x)
#pragma unroll
    for (int q = 0; q < 2; ++q) {
      int idx = q * 512 + t;
      int cl = idx >> 3, uu = idx & 7;
      gload_lds16(whtb + (size_t)cl * 2048 + x * 64 + uu * 8, (char*)&Bb[x][0] + idx * 16);
    }

  for (int jt = 0; jt < 32; ++jt) {
    // B(jt) landed (all but the 2 loads of B(jt+1)); own P ds_writes flushed pre-barrier
    if (jt < 31) asm volatile("s_waitcnt vmcnt(2) lgkmcnt(0)" ::: "memory");
    else         asm volatile("s_waitcnt vmcnt(0) lgkmcnt(0)" ::: "memory");
    __builtin_amdgcn_s_barrier();
    if (jt < 30) {  // issue B(jt+2) into slot (jt+2)%3 (safe: last reads were compute(jt-1))
      const int j0n = (jt + 2) * 64;
      const int p = (jt + 2) % 3;
#pragma unroll
      for (int q = 0; q < 2; ++q) {
        int idx = q * 512 + t;
        int cl = idx >> 3, uu = idx & 7;
        gload_lds16(whtb + (size_t)cl * 2048 + j0n + uu * 8, (char*)&Bb[p][0] + idx * 16);
      }
    }
    if (jt < 31) {  // build P(jt+1)
      const float* sp = &s2s[(jt + 1) * 64 + pj8 * 8];
      float4 v0 = *reinterpret_cast<const float4*>(sp);
      float4 v1 = *reinterpret_cast<const float4*>(sp + 4);
      half8 ph;
      EXP8(ph, v0, v1, C1, C2);
      *reinterpret_cast<half8*>((char*)&Pb[(jt + 1) & 1][0] + pwoff) = ph;
    }
    // compute tile jt (T5: raise wave priority through the MFMA cluster)
    const char* Bc = (const char*)&Bb[jt % 3][0];
    const char* Pc = (const char*)&Pb[jt & 1][0];
    __builtin_amdgcn_s_setprio(1);
#pragma unroll
    for (int kk = 0; kk < 2; ++kk) {
      const int jb = ((lane >> 4) * 8 + kk * 32) * 2;
      const int ar64 = rg * 16 + arow;
      half8 afr = *reinterpret_cast<const half8*>(Pc + ar64 * 128 + (jb ^ ((ar64 & 7) << 4)));
      if (cg == 0)  // denominator: ones-column MFMA (row-sums of fp16 P)
        accd = __builtin_amdgcn_mfma_f32_16x16x32_f16(afr, onesb, accd, 0, 0, 0);
#pragma unroll
      for (int ni = 0; ni < 4; ++ni) {
        int cl = cg * 64 + 16 * ni + arow;
        half8 bfr = *reinterpret_cast<const half8*>(Bc + cl * 128 + (jb ^ ((cl & 7) << 4)));
        acc[ni] = __builtin_amdgcn_mfma_f32_16x16x32_f16(afr, bfr, acc[ni], 0, 0, 0);
      }
    }
    __builtin_amdgcn_s_setprio(0);
  }
  // publish row denominators (col 0 of accd holds row-sums)
  if (cg == 0 && arow == 0) {
#pragma unroll
    for (int reg = 0; reg < 4; ++reg)
      d_lds[rg * 16 + (lane >> 4) * 4 + reg] = accd[reg];
  }
  __syncthreads();
  // epilogue: divide, ELU, store fp32
  const size_t ob = ((size_t)b * 2048 + i0 + rg * 16) * 256 + ch * 128 + cg * 64;
#pragma unroll
  for (int reg = 0; reg < 4; ++reg) {
    int rr = (lane >> 4) * 4 + reg;
    float inv = 1.0f / d_lds[rg * 16 + rr];
#pragma unroll
    for (int ni = 0; ni < 4; ++ni) {
      int c = 16 * ni + arow;
      float v = acc[ni][reg] * inv;
      v = v > 0.f ? v : (__expf(v) - 1.f);
      out[ob + (size_t)rr * 256 + c] = v;
    }
  }
}

extern "C" void kernel_launch(void* const* d_in, const int* in_sizes, int n_in,
                              void* d_out, int out_size, void* d_ws, size_t ws_size,
                              hipStream_t stream) {
  (void)in_sizes; (void)n_in; (void)out_size; (void)ws_size;
  const float* h = (const float*)d_in[0];
  const float* W = (const float*)d_in[1];
  const float* a1 = (const float*)d_in[2];
  const float* a2 = (const float*)d_in[3];
  float* out = (float*)d_out;
  char* ws = (char*)d_ws;
  _Float16* WhT = (_Float16*)(ws);             // 8*256*2048*2 = 8388608 B (pre-swizzled)
  _Float16* W16 = (_Float16*)(ws + 8388608);   // 262144 B (pre-swizzled)
  float* u1 = (float*)(ws + 8650752);          // 2048 B
  float* u2 = (float*)(ws + 8652800);          // 2048 B
  float* s1 = (float*)(ws + 8654848);          // 65536 B
  float* s2 = (float*)(ws + 8720384);          // 65536 B

  hipLaunchKernelGGL(k_prologue, dim3(136), dim3(256), 0, stream, W, a1, a2, W16, u1, u2);
  hipLaunchKernelGGL(k_gemm_wh, dim3(512), dim3(256), 0, stream, h, W16, u1, u2, s1, s2, WhT);
  hipLaunchKernelGGL(k_attn, dim3(512), dim3(512), 0, stream, WhT, s1, s2, out);
}